// Round 10
// baseline (95.142 us; speedup 1.0000x reference)
//
#include <hip/hip_runtime.h>

#define BB 16
#define CH 256
#define NH 4
#define DH 64
#define NN 1024

typedef _Float16 f16x8 __attribute__((ext_vector_type(8)));
typedef float f32x4 __attribute__((ext_vector_type(4)));
typedef float f32x16 __attribute__((ext_vector_type(16)));
typedef unsigned int uint32x4 __attribute__((ext_vector_type(4)));

__device__ __forceinline__ unsigned short f2h(float x) {
    _Float16 h = (_Float16)x;
    return __builtin_bit_cast(unsigned short, h);
}

__device__ __forceinline__ unsigned cvtpk(float a, float b) {
    auto r = __builtin_amdgcn_cvt_pkrtz(a, b);      // low half = a, high = b
    return __builtin_bit_cast(unsigned, r);
}

// ---------------- W -> fp16 (single pass; lo-residual dropped: error ~= fp16
// storage rounding of q/k/v themselves, budget-checked vs 0.085 threshold) ----------------
__global__ __launch_bounds__(256) void prep_kernel(
    const float* __restrict__ Wq, const float* __restrict__ Wk, const float* __restrict__ Wv,
    unsigned short* __restrict__ Wh)
{
    int idx = blockIdx.x * 256 + threadIdx.x;   // 3*CH*CH = 196608
    if (idx >= 3 * CH * CH) return;
    int p = idx >> 16, oc = idx & 65535;
    const float* W = (p == 0) ? Wq : ((p == 1) ? Wk : Wv);
    Wh[idx] = f2h(W[oc]);
}

// ---------------- x fp32 [b][c][n] -> xT fp16 [b][n][c] ----------------
__global__ __launch_bounds__(256) void xt_kernel(
    const float* __restrict__ x, unsigned short* __restrict__ xT)
{
    const int b = blockIdx.z, c0 = blockIdx.y * 32, n0 = blockIdx.x * 32;
    __shared__ float T[32][33];
    const int t = threadIdx.x;
    {
        int c = t >> 3, n4 = (t & 7) * 4;
        float4 v4 = *(const float4*)&x[((size_t)b * CH + c0 + c) * NN + n0 + n4];
        T[c][n4 + 0] = v4.x; T[c][n4 + 1] = v4.y;
        T[c][n4 + 2] = v4.z; T[c][n4 + 3] = v4.w;
    }
    __syncthreads();
    {
        int n = t >> 3, c4 = (t & 7) * 4;
        ushort4 o;
        o.x = f2h(T[c4 + 0][n]); o.y = f2h(T[c4 + 1][n]);
        o.z = f2h(T[c4 + 2][n]); o.w = f2h(T[c4 + 3][n]);
        *(ushort4*)&xT[((size_t)b * NN + n0 + n) * CH + c0 + c4] = o;
    }
}

// ---------------- pos^T fp16: pT[h][n][d] ----------------
__global__ __launch_bounds__(256) void pos_kernel(
    const float* __restrict__ rel_h, const float* __restrict__ rel_w,
    unsigned short* __restrict__ pT)
{
    int idx = blockIdx.x * 256 + threadIdx.x;     // NH*NN*DH = 262144
    if (idx >= NH * NN * DH) return;
    int d = idx & 63, n = (idx >> 6) & (NN - 1), h = idx >> 16;
    float val = rel_w[(h * DH + d) * 32 + (n >> 5)] + rel_h[(h * DH + d) * 32 + (n & 31)];
    pT[idx] = f2h(val);
}

// ---------------- projection via fp16 MFMA (single-pass W) ----------------
__global__ __launch_bounds__(256) void proj_kernel(
    const unsigned short* __restrict__ xT,
    const unsigned short* __restrict__ Wh,
    const float* __restrict__ bq, const float* __restrict__ bk, const float* __restrict__ bv,
    unsigned short* __restrict__ qT, unsigned short* __restrict__ kT,
    unsigned short* __restrict__ vH)
{
    const int bz = blockIdx.z;
    const int b = bz / 3, p = bz % 3;
    const int n0 = blockIdx.x * 64;
    const int o0 = blockIdx.y * 64;
    const float* bias = (p == 0) ? bq : ((p == 1) ? bk : bv);

    __shared__ __align__(16) unsigned short Xs[64][72];
    __shared__ __align__(16) unsigned short Whs[64][72];

    const int tid = threadIdx.x;
    const int wid = tid >> 6, lane = tid & 63;
    const int g = lane >> 4, lr = lane & 15;

    const unsigned short* xb  = xT + (size_t)b * NN * CH;
    const unsigned short* Whp = Wh + (size_t)p * CH * CH;

    const f32x4 z4 = {0.f, 0.f, 0.f, 0.f};
    f32x4 acc[4] = {z4, z4, z4, z4};

    for (int cs = 0; cs < 4; ++cs) {
        const int c0 = cs * 64;
        __syncthreads();
        #pragma unroll
        for (int rep = 0; rep < 2; ++rep) {
            int f = rep * 256 + tid;
            int r = f >> 3, s = f & 7;
            *(uint4*)&Xs[r][s * 8]  = *(const uint4*)&xb[(size_t)(n0 + r) * CH + c0 + s * 8];
            *(uint4*)&Whs[r][s * 8] = *(const uint4*)&Whp[(size_t)(o0 + r) * CH + c0 + s * 8];
        }
        __syncthreads();
        #pragma unroll
        for (int ks = 0; ks < 2; ++ks) {
            f16x8 ah = *(const f16x8*)&Whs[wid * 16 + lr][ks * 32 + g * 8];
            #pragma unroll
            for (int fc = 0; fc < 4; ++fc) {
                f16x8 bx = *(const f16x8*)&Xs[fc * 16 + lr][ks * 32 + g * 8];
                acc[fc] = __builtin_amdgcn_mfma_f32_16x16x32_f16(ah, bx, acc[fc], 0, 0, 0);
            }
        }
    }

    float bb[4];
    #pragma unroll
    for (int rr = 0; rr < 4; ++rr) bb[rr] = bias[o0 + wid * 16 + g * 4 + rr];

    if (p < 2) {
        const float scale = (p == 0) ? 1.44269504088896f : 1.0f;   // fold log2e into q
        __syncthreads();
        unsigned short (*Os)[72] = Whs;     // reuse as [n-local][o-local]
        #pragma unroll
        for (int fc = 0; fc < 4; ++fc)
            #pragma unroll
            for (int rr = 0; rr < 4; ++rr)
                Os[fc * 16 + lr][wid * 16 + g * 4 + rr] = f2h((acc[fc][rr] + bb[rr]) * scale);
        __syncthreads();
        unsigned short* dst = ((p == 0) ? qT : kT) + ((size_t)(b * NH + blockIdx.y) * NN + n0) * DH;
        #pragma unroll
        for (int rep = 0; rep < 2; ++rep) {
            int f = rep * 256 + tid;
            int r = f >> 3, s = f & 7;
            *(uint4*)&dst[(size_t)r * DH + s * 8] = *(const uint4*)&Os[r][s * 8];
        }
    } else {
        unsigned short* dv = vH + (size_t)b * CH * NN;
        #pragma unroll
        for (int fc = 0; fc < 4; ++fc)
            #pragma unroll
            for (int rr = 0; rr < 4; ++rr) {
                int o = o0 + wid * 16 + g * 4 + rr;
                dv[(size_t)o * NN + n0 + fc * 16 + lr] = f2h(acc[fc][rr] + bb[rr]);
            }
    }
}

// ---------------- fused flash attention: 32x32 swapped-QK^T, wave_i = 64 ----------------
// R9 post-mortem: LDS read pipe was ~100% busy (each wave reads the FULL K/V tile
// regardless of i-width -> 4x duplication). Fix: each wave owns TWO 32-col i-groups;
// K A-frags and V B-frags are read ONCE and feed both groups' MFMAs -> LDS bytes per
// S-element halve. Block = 4 waves x 64 i = 256 i; grid = 256 (1 block/CU, 1 wave/SIMD;
// __launch_bounds__(256,1) -> full VGPR budget, no spill).
// All layouts identical to the verified R9 kernel (zero-exchange PV k-permutation).
__global__ __launch_bounds__(256, 1) void attn_kernel(
    const unsigned short* __restrict__ qT, const unsigned short* __restrict__ kT,
    const unsigned short* __restrict__ vH, const unsigned short* __restrict__ pT,
    float* __restrict__ out)
{
    const int wg = blockIdx.x;                       // 0..255
    const int bh = (wg & 7) * 8 + ((wg >> 3) & 7);   // XCD-bijective: 8 (b,h) per XCD
    const int it = wg >> 6;                          // 0..3
    const int b = bh >> 2, h = bh & 3;
    const int i0 = it * 256;

    // K: 2 x [64 rows][128 halves] (16KB each). V: 2 x [32 rows][128 halves] (8KB each).
    __shared__ __align__(16) unsigned short KV[24576];      // 48 KB
    __shared__ __align__(16) float Lbuf[256];
    float* Epi = (float*)KV;                                // [64][132] f32 alias (33.8KB)

    const int tid = threadIdx.x;
    const int wid = tid >> 6, lane = tid & 63;
    const int l31 = lane & 31, hi = lane >> 5;

    const size_t bhNN = (size_t)(b * NH + h) * NN;
    const unsigned short* qTb = qT + bhNN * DH;
    const unsigned short* kTb = kT + bhNN * DH;
    const unsigned short* pTb = pT + (size_t)h * NN * DH;
    const unsigned short* vb  = vH + ((size_t)b * CH + h * DH) * NN;

    // Q-ext B-fragments for both i-groups: d = ks*16 + hi*8 + e
    f16x8 bQ0[8], bQ1[8];
    {
        const int ia = i0 + wid * 64 + l31;
        const int ib = ia + 32;
        #pragma unroll
        for (int ks = 0; ks < 8; ++ks) {
            int d0 = ks * 16 + hi * 8;
            const unsigned short* sa = (d0 < 64) ? &qTb[(size_t)ia * DH + d0]
                                                 : &pTb[(size_t)ia * DH + d0 - 64];
            const unsigned short* sb = (d0 < 64) ? &qTb[(size_t)ib * DH + d0]
                                                 : &pTb[(size_t)ib * DH + d0 - 64];
            bQ0[ks] = *(const f16x8*)sa;
            bQ1[ks] = *(const f16x8*)sb;
        }
    }

    const int srow = tid >> 4;       // 0..15
    const int sslot = tid & 15;
    // V store permutation constants (zero-exchange PV k-order; verified R9)
    const int vc = sslot & 7;
    const int vM = ((vc >> 1) << 2) + (vc & 1) + ((sslot & 8) << 1);
    const int vs8 = vM >> 1;
    const int vnib = (vM & 1) * 4;
    uint4 kst[4], vst[2];

    #define STAGE_LOAD(jb)                                                                  \
        {                                                                                   \
            _Pragma("unroll")                                                               \
            for (int rep = 0; rep < 4; ++rep) {                                             \
                int row = rep * 16 + srow;                                                  \
                const unsigned short* src = ((sslot < 8) ? kTb : qTb)                       \
                    + (size_t)((jb) + row) * DH + (sslot & 7) * 8;                          \
                kst[rep] = *(const uint4*)src;                                              \
            }                                                                               \
            _Pragma("unroll")                                                               \
            for (int rep = 0; rep < 2; ++rep) {                                             \
                int row = rep * 16 + srow;                                                  \
                int d = row + ((sslot & 8) << 2);                                           \
                vst[rep] = *(const uint4*)&vb[(size_t)d * NN + (jb) + (sslot & 7) * 8];     \
            }                                                                               \
        }

    #define STAGE_WRITE(buf)                                                                \
        {                                                                                   \
            unsigned short* Kb = KV + (buf) * 8192;                                         \
            unsigned short* Vb = KV + 16384 + (buf) * 4096;                                 \
            _Pragma("unroll")                                                               \
            for (int rep = 0; rep < 4; ++rep) {                                             \
                int row = rep * 16 + srow;                                                  \
                *(uint4*)&Kb[row * 128 + ((sslot ^ (row & 15)) << 3)] = kst[rep];           \
            }                                                                               \
            _Pragma("unroll")                                                               \
            for (int rep = 0; rep < 2; ++rep) {                                             \
                int row = rep * 16 + srow;                                                  \
                uint2 vlo; vlo.x = vst[rep].x; vlo.y = vst[rep].y;                          \
                uint2 vhi2; vhi2.x = vst[rep].z; vhi2.y = vst[rep].w;                       \
                *(uint2*)&Vb[row * 128 + ((vs8 ^ (row & 15)) << 3) + vnib] = vlo;           \
                *(uint2*)&Vb[row * 128 + (((vs8 + 1) ^ (row & 15)) << 3) + vnib] = vhi2;    \
            }                                                                               \
        }

    // defer-max softmax + fp16 pack for one i-group (slow-path sc broadcast via __shfl)
    #define SOFTMAX_GRP(S0, S1, MR, LR, C0, C1, OA, OB)                                     \
        {                                                                                   \
            float fm = S0[0];                                                               \
            _Pragma("unroll") for (int r = 1; r < 16; ++r) fm = fmaxf(fm, S0[r]);           \
            _Pragma("unroll") for (int r = 0; r < 16; ++r) fm = fmaxf(fm, S1[r]);           \
            if (!__all(fm <= MR + 8.f)) {                                                   \
                float fmf = fmaxf(fm, __shfl_xor(fm, 32));                                  \
                float mn = fmaxf(MR, fmf);                                                  \
                float sc = exp2f(MR - mn);                                                  \
                MR = mn; LR *= sc;                                                          \
                _Pragma("unroll") for (int r = 0; r < 16; ++r) {                            \
                    int irow = (r & 3) + 8 * (r >> 2) + 4 * hi;                             \
                    float scv = __shfl(sc, irow);                                           \
                    OA[r] *= scv; OB[r] *= scv;                                             \
                }                                                                           \
            }                                                                               \
            float ps = 0.f;                                                                 \
            _Pragma("unroll") for (int m = 0; m < 8; ++m) {                                 \
                float pa = exp2f(S0[2 * m]     - MR);                                       \
                float pb = exp2f(S0[2 * m + 1] - MR);                                       \
                float pc = exp2f(S1[2 * m]     - MR);                                       \
                float pd = exp2f(S1[2 * m + 1] - MR);                                       \
                ps += (pa + pb) + (pc + pd);                                                \
                C0[m] = cvtpk(pa, pb);                                                      \
                C1[m] = cvtpk(pc, pd);                                                      \
            }                                                                               \
            LR += ps;                                                                       \
        }

    f32x16 O00 = {}, O01 = {}, O10 = {}, O11 = {};   // [grp][d-half]
    float m0 = -1e30f, m1 = -1e30f, l0 = 0.f, l1 = 0.f;

    STAGE_LOAD(0);
    STAGE_WRITE(0);

    for (int t = 0; t < 16; ++t) {
        __syncthreads();                        // buf[t&1] visible
        if (t < 15) STAGE_LOAD((t + 1) * 64);   // 1 tile ahead; full compute phase of slack

        const unsigned short* Kb = KV + (t & 1) * 8192;
        const unsigned short* Vb = KV + 16384 + (t & 1) * 4096;

        // ---- QK^T: K A-frags read ONCE, feed both i-groups ----
        f32x16 s0g0 = {}, s1g0 = {}, s0g1 = {}, s1g1 = {};
        __builtin_amdgcn_s_setprio(1);
        #pragma unroll
        for (int ks = 0; ks < 8; ++ks) {
            int r0 = l31, r1 = 32 + l31;
            int slot = ks * 2 + hi;
            f16x8 a0 = *(const f16x8*)&Kb[r0 * 128 + ((slot ^ (r0 & 15)) << 3)];
            f16x8 a1 = *(const f16x8*)&Kb[r1 * 128 + ((slot ^ (r1 & 15)) << 3)];
            s0g0 = __builtin_amdgcn_mfma_f32_32x32x16_f16(a0, bQ0[ks], s0g0, 0, 0, 0);
            s1g0 = __builtin_amdgcn_mfma_f32_32x32x16_f16(a1, bQ0[ks], s1g0, 0, 0, 0);
            s0g1 = __builtin_amdgcn_mfma_f32_32x32x16_f16(a0, bQ1[ks], s0g1, 0, 0, 0);
            s1g1 = __builtin_amdgcn_mfma_f32_32x32x16_f16(a1, bQ1[ks], s1g1, 0, 0, 0);
        }
        __builtin_amdgcn_s_setprio(0);

        // ---- V B-frags hoisted (read once; overlap LDS latency with softmax) ----
        f16x8 vf0[4], vf1[4];
        #pragma unroll
        for (int u = 0; u < 4; ++u) {
            int rv = l31;
            int sl0 = (u * 2 + hi) ^ (rv & 15);
            int sl1 = (8 + u * 2 + hi) ^ (rv & 15);
            vf0[u] = *(const f16x8*)&Vb[rv * 128 + (sl0 << 3)];
            vf1[u] = *(const f16x8*)&Vb[rv * 128 + (sl1 << 3)];
        }

        // ---- softmax per group (log2 domain, defer-max THR=8) ----
        unsigned c0A[8], c1A[8], c0B[8], c1B[8];
        SOFTMAX_GRP(s0g0, s1g0, m0, l0, c0A, c1A, O00, O01);
        SOFTMAX_GRP(s0g1, s1g1, m1, l1, c0B, c1B, O10, O11);

        // ---- PV A-frags: lane's own words (zero exchange) ----
        f16x8 pA0[4], pA1[4];
        #pragma unroll
        for (int u = 0; u < 4; ++u) {
            int ksi = u & 1;
            unsigned* ca = (u >> 1) ? c1A : c0A;
            unsigned* cb = (u >> 1) ? c1B : c0B;
            uint32x4 wa = { ca[ksi * 4 + 0], ca[ksi * 4 + 1], ca[ksi * 4 + 2], ca[ksi * 4 + 3] };
            uint32x4 wb = { cb[ksi * 4 + 0], cb[ksi * 4 + 1], cb[ksi * 4 + 2], cb[ksi * 4 + 3] };
            pA0[u] = __builtin_bit_cast(f16x8, wa);
            pA1[u] = __builtin_bit_cast(f16x8, wb);
        }

        // ---- PV: V frags shared across both groups ----
        __builtin_amdgcn_s_setprio(1);
        #pragma unroll
        for (int u = 0; u < 4; ++u) {
            O00 = __builtin_amdgcn_mfma_f32_32x32x16_f16(pA0[u], vf0[u], O00, 0, 0, 0);
            O01 = __builtin_amdgcn_mfma_f32_32x32x16_f16(pA0[u], vf1[u], O01, 0, 0, 0);
            O10 = __builtin_amdgcn_mfma_f32_32x32x16_f16(pA1[u], vf0[u], O10, 0, 0, 0);
            O11 = __builtin_amdgcn_mfma_f32_32x32x16_f16(pA1[u], vf1[u], O11, 0, 0, 0);
        }
        __builtin_amdgcn_s_setprio(0);

        if (t < 15) STAGE_WRITE((t + 1) & 1);
    }

    // ---- epilogue: pair-sum l, two-half LDS transpose (Epi = 64 x 132 f32), store ----
    float l0f = l0 + __shfl_xor(l0, 32);
    float l1f = l1 + __shfl_xor(l1, 32);
    __syncthreads();                      // all waves done reading KV
    if (lane < 32) {
        Lbuf[wid * 64 + l31]      = 1.0f / l0f;
        Lbuf[wid * 64 + 32 + l31] = 1.0f / l1f;
    }
    float* ob = out + ((size_t)b * CH + h * DH) * NN + i0;
    #pragma unroll
    for (int half = 0; half < 2; ++half) {
        if ((wid >> 1) == half) {
            int ibr = (wid & 1) * 64;
            #pragma unroll
            for (int r = 0; r < 16; ++r) {
                int irow = (r & 3) + 8 * (r >> 2) + 4 * hi;
                Epi[l31 * 132        + ibr + irow]      = O00[r];
                Epi[(32 + l31) * 132 + ibr + irow]      = O01[r];
                Epi[l31 * 132        + ibr + 32 + irow] = O10[r];
                Epi[(32 + l31) * 132 + ibr + 32 + irow] = O11[r];
            }
        }
        __syncthreads();
        #pragma unroll
        for (int rep = 0; rep < 8; ++rep) {
            int f = rep * 256 + tid;
            int d = f >> 5, q = f & 31;
            float4 v4 = *(const float4*)&Epi[d * 132 + q * 4];
            float4 iv = *(const float4*)&Lbuf[half * 128 + q * 4];
            v4.x *= iv.x; v4.y *= iv.y; v4.z *= iv.z; v4.w *= iv.w;
            *(float4*)&ob[(size_t)d * NN + half * 128 + q * 4] = v4;
        }
        __syncthreads();
    }
}

extern "C" void kernel_launch(void* const* d_in, const int* in_sizes, int n_in,
                              void* d_out, int out_size, void* d_ws, size_t ws_size,
                              hipStream_t stream) {
    const float* x     = (const float*)d_in[0];
    const float* Wq    = (const float*)d_in[1];
    const float* bq    = (const float*)d_in[2];
    const float* Wk    = (const float*)d_in[3];
    const float* bk    = (const float*)d_in[4];
    const float* Wv    = (const float*)d_in[5];
    const float* bv    = (const float*)d_in[6];
    const float* rel_h = (const float*)d_in[7];
    const float* rel_w = (const float*)d_in[8];
    // d_in[9] (reg_qk), d_in[10] (reg_v): dead — reference discards the register-token group.
    float* out = (float*)d_out;

    const size_t SZ = (size_t)BB * NH * NN * DH;        // 4,194,304
    unsigned short* qT = (unsigned short*)d_ws;
    unsigned short* kT = qT + SZ;
    unsigned short* vH = kT + SZ;
    unsigned short* pT = vH + SZ;                       // NH*NN*DH = 262,144
    unsigned short* xT = pT + (size_t)NH * NN * DH;     // BB*NN*CH = 4,194,304
    unsigned short* Wh = xT + SZ;                       // 3*CH*CH = 196,608

    prep_kernel<<<dim3((3 * CH * CH + 255) / 256), 256, 0, stream>>>(Wq, Wk, Wv, Wh);
    xt_kernel<<<dim3(NN / 32, CH / 32, BB), 256, 0, stream>>>(x, xT);
    pos_kernel<<<dim3((NH * NN * DH + 255) / 256), 256, 0, stream>>>(rel_h, rel_w, pT);
    proj_kernel<<<dim3(NN / 64, CH / 64, BB * 3), 256, 0, stream>>>(
        xT, Wh, bq, bk, bv, qT, kT, vH);
    attn_kernel<<<dim3(256), 256, 0, stream>>>(qT, kT, vH, pT, out);
}

// Round 11
// 93.888 us; speedup vs baseline: 1.0134x; 1.0134x over previous
//
#include <hip/hip_runtime.h>

#define BB 16
#define CH 256
#define NH 4
#define DH 64
#define NN 1024

typedef _Float16 f16x8 __attribute__((ext_vector_type(8)));
typedef float f32x4 __attribute__((ext_vector_type(4)));
typedef float f32x16 __attribute__((ext_vector_type(16)));
typedef unsigned int uint32x4 __attribute__((ext_vector_type(4)));

__device__ __forceinline__ unsigned short f2h(float x) {
    _Float16 h = (_Float16)x;
    return __builtin_bit_cast(unsigned short, h);
}

__device__ __forceinline__ unsigned cvtpk(float a, float b) {
    auto r = __builtin_amdgcn_cvt_pkrtz(a, b);      // low half = a, high = b
    return __builtin_bit_cast(unsigned, r);
}

// ---------------- W -> fp16 (single pass; absmax-verified in R10) ----------------
__global__ __launch_bounds__(256) void prep_kernel(
    const float* __restrict__ Wq, const float* __restrict__ Wk, const float* __restrict__ Wv,
    unsigned short* __restrict__ Wh)
{
    int idx = blockIdx.x * 256 + threadIdx.x;   // 3*CH*CH = 196608
    if (idx >= 3 * CH * CH) return;
    int p = idx >> 16, oc = idx & 65535;
    const float* W = (p == 0) ? Wq : ((p == 1) ? Wk : Wv);
    Wh[idx] = f2h(W[oc]);
}

// ---------------- x fp32 [b][c][n] -> xT fp16 [b][n][c] ----------------
__global__ __launch_bounds__(256) void xt_kernel(
    const float* __restrict__ x, unsigned short* __restrict__ xT)
{
    const int b = blockIdx.z, c0 = blockIdx.y * 32, n0 = blockIdx.x * 32;
    __shared__ float T[32][33];
    const int t = threadIdx.x;
    {
        int c = t >> 3, n4 = (t & 7) * 4;
        float4 v4 = *(const float4*)&x[((size_t)b * CH + c0 + c) * NN + n0 + n4];
        T[c][n4 + 0] = v4.x; T[c][n4 + 1] = v4.y;
        T[c][n4 + 2] = v4.z; T[c][n4 + 3] = v4.w;
    }
    __syncthreads();
    {
        int n = t >> 3, c4 = (t & 7) * 4;
        ushort4 o;
        o.x = f2h(T[c4 + 0][n]); o.y = f2h(T[c4 + 1][n]);
        o.z = f2h(T[c4 + 2][n]); o.w = f2h(T[c4 + 3][n]);
        *(ushort4*)&xT[((size_t)b * NN + n0 + n) * CH + c0 + c4] = o;
    }
}

// ---------------- pos^T fp16: pT[h][n][d] ----------------
__global__ __launch_bounds__(256) void pos_kernel(
    const float* __restrict__ rel_h, const float* __restrict__ rel_w,
    unsigned short* __restrict__ pT)
{
    int idx = blockIdx.x * 256 + threadIdx.x;     // NH*NN*DH = 262144
    if (idx >= NH * NN * DH) return;
    int d = idx & 63, n = (idx >> 6) & (NN - 1), h = idx >> 16;
    float val = rel_w[(h * DH + d) * 32 + (n >> 5)] + rel_h[(h * DH + d) * 32 + (n & 31)];
    pT[idx] = f2h(val);
}

// ---------------- FUSED projection: xT tile staged ONCE, loop p x o-tile ----------------
// R10 post-mortem: standalone proj was memory-bound re-reading xT 3x (24MB).
// Grid (16 n-tiles, 16 b); block stages Xs[64n][256c] once (32KB), then 12 phases
// (3 proj x 4 o-tiles) stage only W tiles from L2 (384KB total, L2-resident).
__global__ __launch_bounds__(256) void proj_kernel(
    const unsigned short* __restrict__ xT,
    const unsigned short* __restrict__ Wh,
    const float* __restrict__ bq, const float* __restrict__ bk, const float* __restrict__ bv,
    unsigned short* __restrict__ qT, unsigned short* __restrict__ kT,
    unsigned short* __restrict__ vH)
{
    const int n0 = blockIdx.x * 64;
    const int b  = blockIdx.y;

    __shared__ __align__(16) unsigned short Xs[64][264];   // [n][c], pad 8
    __shared__ __align__(16) unsigned short Ws[64][264];   // [o][c], pad 8 (reused as epilogue Os)

    const int tid = threadIdx.x;
    const int wid = tid >> 6, lane = tid & 63;
    const int g = lane >> 4, lr = lane & 15;

    const unsigned short* xb = xT + (size_t)b * NN * CH;

    // stage Xs once: 64 rows x 256 halves
    #pragma unroll
    for (int rep = 0; rep < 8; ++rep) {
        int f = rep * 256 + tid;
        int n = f >> 5, s = f & 31;
        *(uint4*)&Xs[n][s * 8] = *(const uint4*)&xb[(size_t)(n0 + n) * CH + s * 8];
    }

    const f32x4 z4 = {0.f, 0.f, 0.f, 0.f};

    for (int p = 0; p < 3; ++p) {
        const unsigned short* Wp = Wh + (size_t)p * CH * CH;
        const float* bias = (p == 0) ? bq : ((p == 1) ? bk : bv);
        for (int ot = 0; ot < 4; ++ot) {
            const int o0 = ot * 64;
            __syncthreads();    // Ws free (previous phase done) / Xs ready (first phase)
            #pragma unroll
            for (int rep = 0; rep < 8; ++rep) {
                int f = rep * 256 + tid;
                int r = f >> 5, s = f & 31;
                *(uint4*)&Ws[r][s * 8] = *(const uint4*)&Wp[(size_t)(o0 + r) * CH + s * 8];
            }
            __syncthreads();

            f32x4 acc[4] = {z4, z4, z4, z4};
            #pragma unroll
            for (int cs = 0; cs < 4; ++cs) {
                #pragma unroll
                for (int ks = 0; ks < 2; ++ks) {
                    f16x8 ah = *(const f16x8*)&Ws[wid * 16 + lr][cs * 64 + ks * 32 + g * 8];
                    #pragma unroll
                    for (int fc = 0; fc < 4; ++fc) {
                        f16x8 bx = *(const f16x8*)&Xs[fc * 16 + lr][cs * 64 + ks * 32 + g * 8];
                        acc[fc] = __builtin_amdgcn_mfma_f32_16x16x32_f16(ah, bx, acc[fc], 0, 0, 0);
                    }
                }
            }

            float bb[4];
            #pragma unroll
            for (int rr = 0; rr < 4; ++rr) bb[rr] = bias[o0 + wid * 16 + g * 4 + rr];

            if (p < 2) {
                const float scale = (p == 0) ? 1.44269504088896f : 1.0f;  // fold log2e into q
                __syncthreads();    // all A-frag reads of Ws complete
                unsigned short (*Os)[264] = Ws;     // reuse as [n-local][o-local]
                #pragma unroll
                for (int fc = 0; fc < 4; ++fc)
                    #pragma unroll
                    for (int rr = 0; rr < 4; ++rr)
                        Os[fc * 16 + lr][wid * 16 + g * 4 + rr] = f2h((acc[fc][rr] + bb[rr]) * scale);
                __syncthreads();
                unsigned short* dst = ((p == 0) ? qT : kT) + ((size_t)(b * NH + ot) * NN + n0) * DH;
                #pragma unroll
                for (int rep = 0; rep < 2; ++rep) {
                    int f = rep * 256 + tid;
                    int r = f >> 3, s = f & 7;
                    *(uint4*)&dst[(size_t)r * DH + s * 8] = *(const uint4*)&Os[r][s * 8];
                }
            } else {
                unsigned short* dv = vH + (size_t)b * CH * NN;
                #pragma unroll
                for (int fc = 0; fc < 4; ++fc)
                    #pragma unroll
                    for (int rr = 0; rr < 4; ++rr) {
                        int o = o0 + wid * 16 + g * 4 + rr;
                        dv[(size_t)o * NN + n0 + fc * 16 + lr] = f2h(acc[fc][rr] + bb[rr]);
                    }
            }
        }
    }
}

// ---------------- fused flash attention (byte-exact R9, verified 62.7us) ----------------
// 32x32 swapped-QK^T, in-register softmax, zero-exchange PV k-permutation,
// double-buffered K/V with 16-slot XOR swizzle, one barrier/iter.
__global__ __launch_bounds__(256, 2) void attn_kernel(
    const unsigned short* __restrict__ qT, const unsigned short* __restrict__ kT,
    const unsigned short* __restrict__ vH, const unsigned short* __restrict__ pT,
    float* __restrict__ out)
{
    const int wg = blockIdx.x;                       // 0..511
    const int bh = (wg & 7) * 8 + ((wg >> 3) & 7);   // XCD-bijective: 8 (b,h) per XCD
    const int it = wg >> 6;                          // 0..7
    const int b = bh >> 2, h = bh & 3;
    const int i0 = it * 128;

    __shared__ __align__(16) unsigned short KV[24576];      // 48 KB
    __shared__ __align__(16) float Lbuf[128];
    __shared__ float ScBuf[4][32];
    float* Epi = (float*)KV;                                // [64][132] f32 alias

    const int tid = threadIdx.x;
    const int wid = tid >> 6, lane = tid & 63;
    const int l31 = lane & 31, hi = lane >> 5;

    const size_t bhNN = (size_t)(b * NH + h) * NN;
    const unsigned short* qTb = qT + bhNN * DH;
    const unsigned short* kTb = kT + bhNN * DH;
    const unsigned short* pTb = pT + (size_t)h * NN * DH;
    const unsigned short* vb  = vH + ((size_t)b * CH + h * DH) * NN;

    f16x8 bQ[8];
    {
        const int i = i0 + wid * 32 + l31;
        #pragma unroll
        for (int ks = 0; ks < 8; ++ks) {
            int d0 = ks * 16 + hi * 8;
            const unsigned short* src = (d0 < 64) ? &qTb[(size_t)i * DH + d0]
                                                  : &pTb[(size_t)i * DH + d0 - 64];
            bQ[ks] = *(const f16x8*)src;
        }
    }

    const int srow = tid >> 4;       // 0..15
    const int sslot = tid & 15;
    const int vc = sslot & 7;
    const int vM = ((vc >> 1) << 2) + (vc & 1) + ((sslot & 8) << 1);
    const int vs8 = vM >> 1;
    const int vnib = (vM & 1) * 4;
    uint4 kst[4], vst[2];

    #define STAGE_LOAD(jb)                                                                  \
        {                                                                                   \
            _Pragma("unroll")                                                               \
            for (int rep = 0; rep < 4; ++rep) {                                             \
                int row = rep * 16 + srow;                                                  \
                const unsigned short* src = ((sslot < 8) ? kTb : qTb)                       \
                    + (size_t)((jb) + row) * DH + (sslot & 7) * 8;                          \
                kst[rep] = *(const uint4*)src;                                              \
            }                                                                               \
            _Pragma("unroll")                                                               \
            for (int rep = 0; rep < 2; ++rep) {                                             \
                int row = rep * 16 + srow;                                                  \
                int d = row + ((sslot & 8) << 2);                                           \
                vst[rep] = *(const uint4*)&vb[(size_t)d * NN + (jb) + (sslot & 7) * 8];     \
            }                                                                               \
        }

    #define STAGE_WRITE(buf)                                                                \
        {                                                                                   \
            unsigned short* Kb = KV + (buf) * 8192;                                         \
            unsigned short* Vb = KV + 16384 + (buf) * 4096;                                 \
            _Pragma("unroll")                                                               \
            for (int rep = 0; rep < 4; ++rep) {                                             \
                int row = rep * 16 + srow;                                                  \
                *(uint4*)&Kb[row * 128 + ((sslot ^ (row & 15)) << 3)] = kst[rep];           \
            }                                                                               \
            _Pragma("unroll")                                                               \
            for (int rep = 0; rep < 2; ++rep) {                                             \
                int row = rep * 16 + srow;                                                  \
                uint2 vlo; vlo.x = vst[rep].x; vlo.y = vst[rep].y;                          \
                uint2 vhi2; vhi2.x = vst[rep].z; vhi2.y = vst[rep].w;                       \
                *(uint2*)&Vb[row * 128 + ((vs8 ^ (row & 15)) << 3) + vnib] = vlo;           \
                *(uint2*)&Vb[row * 128 + (((vs8 + 1) ^ (row & 15)) << 3) + vnib] = vhi2;    \
            }                                                                               \
        }

    f32x16 O0 = {}, O1 = {};
    float m_run = -1e30f, l_run = 0.f;

    STAGE_LOAD(0);
    STAGE_WRITE(0);

    for (int t = 0; t < 16; ++t) {
        __syncthreads();                    // buf[t&1] visible to all waves
        if (t < 15) STAGE_LOAD((t + 1) * 64);   // after barrier: hidden under compute

        const unsigned short* Kb = KV + (t & 1) * 8192;
        const unsigned short* Vb = KV + 16384 + (t & 1) * 4096;

        // ---- QK^T (swapped): two 32x32 S^T subtiles ----
        f32x16 s0 = {}, s1 = {};
        __builtin_amdgcn_s_setprio(1);
        #pragma unroll
        for (int ks = 0; ks < 8; ++ks) {
            int r0 = l31, r1 = 32 + l31;
            int slot = ks * 2 + hi;
            f16x8 a0 = *(const f16x8*)&Kb[r0 * 128 + ((slot ^ (r0 & 15)) << 3)];
            f16x8 a1 = *(const f16x8*)&Kb[r1 * 128 + ((slot ^ (r1 & 15)) << 3)];
            s0 = __builtin_amdgcn_mfma_f32_32x32x16_f16(a0, bQ[ks], s0, 0, 0, 0);
            s1 = __builtin_amdgcn_mfma_f32_32x32x16_f16(a1, bQ[ks], s1, 0, 0, 0);
        }
        __builtin_amdgcn_s_setprio(0);

        // ---- defer-max online softmax (log2 domain), fully in-lane ----
        float fm = s0[0];
        #pragma unroll
        for (int r = 1; r < 16; ++r) fm = fmaxf(fm, s0[r]);
        #pragma unroll
        for (int r = 0; r < 16; ++r) fm = fmaxf(fm, s1[r]);

        if (!__all(fm <= m_run + 8.f)) {
            float fmf = fmaxf(fm, __shfl_xor(fm, 32));   // pair-lane: full row max
            float mn = fmaxf(m_run, fmf);
            float sc = exp2f(m_run - mn);
            m_run = mn;
            l_run *= sc;
            if (lane < 32) ScBuf[wid][lane] = sc;        // sc for softmax row i = lane
            #pragma unroll
            for (int r = 0; r < 16; ++r) {
                int irow = (r & 3) + 8 * (r >> 2) + 4 * hi;
                float scv = ScBuf[wid][irow];
                O0[r] *= scv; O1[r] *= scv;
            }
        }

        // ---- P = exp2(S - m): pack fp16 pairs, sum in-lane ----
        unsigned c0[8], c1[8];
        float ps = 0.f;
        #pragma unroll
        for (int m = 0; m < 8; ++m) {
            float pa = exp2f(s0[2 * m]     - m_run);
            float pb = exp2f(s0[2 * m + 1] - m_run);
            float pc = exp2f(s1[2 * m]     - m_run);
            float pd = exp2f(s1[2 * m + 1] - m_run);
            ps += (pa + pb) + (pc + pd);
            c0[m] = cvtpk(pa, pb);
            c1[m] = cvtpk(pc, pd);
        }
        l_run += ps;

        // ---- PV A-frags: lane's own words, zero exchange ----
        f16x8 pA[2][2];
        #pragma unroll
        for (int js = 0; js < 2; ++js) {
            unsigned* c = js ? c1 : c0;
            #pragma unroll
            for (int ksi = 0; ksi < 2; ++ksi) {
                uint32x4 w = { c[ksi * 4 + 0], c[ksi * 4 + 1], c[ksi * 4 + 2], c[ksi * 4 + 3] };
                pA[js][ksi] = __builtin_bit_cast(f16x8, w);
            }
        }

        // ---- PV: O[i][d] += P * V ----
        __builtin_amdgcn_s_setprio(1);
        #pragma unroll
        for (int js = 0; js < 2; ++js) {
            #pragma unroll
            for (int ksi = 0; ksi < 2; ++ksi) {
                int rv = l31;
                int sl0 = (js * 4 + ksi * 2 + hi) ^ (rv & 15);
                int sl1 = (8 + js * 4 + ksi * 2 + hi) ^ (rv & 15);
                f16x8 v0 = *(const f16x8*)&Vb[rv * 128 + (sl0 << 3)];
                f16x8 v1 = *(const f16x8*)&Vb[rv * 128 + (sl1 << 3)];
                O0 = __builtin_amdgcn_mfma_f32_32x32x16_f16(pA[js][ksi], v0, O0, 0, 0, 0);
                O1 = __builtin_amdgcn_mfma_f32_32x32x16_f16(pA[js][ksi], v1, O1, 0, 0, 0);
            }
        }
        __builtin_amdgcn_s_setprio(0);

        if (t < 15) STAGE_WRITE((t + 1) & 1);    // vmcnt wait lands here, post-compute
    }

    // ---- epilogue: pair-sum l, LDS transpose, normalized coalesced store ----
    float l_full = l_run + __shfl_xor(l_run, 32);
    float invl = 1.0f / l_full;
    __syncthreads();                      // done reading KV before Epi overwrite
    if (lane < 32) Lbuf[wid * 32 + lane] = invl;
    #pragma unroll
    for (int r = 0; r < 16; ++r) {
        int irow = (r & 3) + 8 * (r >> 2) + 4 * hi;
        int ilocal = wid * 32 + irow;
        Epi[(l31) * 132 + ilocal]      = O0[r];
        Epi[(32 + l31) * 132 + ilocal] = O1[r];
    }
    __syncthreads();
    float* ob = out + ((size_t)b * CH + h * DH) * NN + i0;
    #pragma unroll
    for (int rep = 0; rep < 8; ++rep) {
        int f = rep * 256 + tid;
        int d = f >> 5, q = f & 31;
        float4 v4 = *(const float4*)&Epi[d * 132 + q * 4];
        float4 iv = *(const float4*)&Lbuf[q * 4];
        v4.x *= iv.x; v4.y *= iv.y; v4.z *= iv.z; v4.w *= iv.w;
        *(float4*)&ob[(size_t)d * NN + q * 4] = v4;
    }
}

extern "C" void kernel_launch(void* const* d_in, const int* in_sizes, int n_in,
                              void* d_out, int out_size, void* d_ws, size_t ws_size,
                              hipStream_t stream) {
    const float* x     = (const float*)d_in[0];
    const float* Wq    = (const float*)d_in[1];
    const float* bq    = (const float*)d_in[2];
    const float* Wk    = (const float*)d_in[3];
    const float* bk    = (const float*)d_in[4];
    const float* Wv    = (const float*)d_in[5];
    const float* bv    = (const float*)d_in[6];
    const float* rel_h = (const float*)d_in[7];
    const float* rel_w = (const float*)d_in[8];
    // d_in[9] (reg_qk), d_in[10] (reg_v): dead — reference discards the register-token group.
    float* out = (float*)d_out;

    const size_t SZ = (size_t)BB * NH * NN * DH;        // 4,194,304
    unsigned short* qT = (unsigned short*)d_ws;
    unsigned short* kT = qT + SZ;
    unsigned short* vH = kT + SZ;
    unsigned short* pT = vH + SZ;                       // NH*NN*DH = 262,144
    unsigned short* xT = pT + (size_t)NH * NN * DH;     // BB*NN*CH = 4,194,304
    unsigned short* Wh = xT + SZ;                       // 3*CH*CH = 196,608

    prep_kernel<<<dim3((3 * CH * CH + 255) / 256), 256, 0, stream>>>(Wq, Wk, Wv, Wh);
    xt_kernel<<<dim3(NN / 32, CH / 32, BB), 256, 0, stream>>>(x, xT);
    pos_kernel<<<dim3((NH * NN * DH + 255) / 256), 256, 0, stream>>>(rel_h, rel_w, pT);
    proj_kernel<<<dim3(NN / 64, BB), 256, 0, stream>>>(xT, Wh, bq, bk, bv, qT, kT, vH);
    attn_kernel<<<dim3(512), 256, 0, stream>>>(qT, kT, vH, pT, out);
}

// Round 12
// 92.951 us; speedup vs baseline: 1.0236x; 1.0101x over previous
//
#include <hip/hip_runtime.h>

#define BB 16
#define CH 256
#define NH 4
#define DH 64
#define NN 1024

typedef _Float16 f16x8 __attribute__((ext_vector_type(8)));
typedef float f32x4 __attribute__((ext_vector_type(4)));
typedef float f32x16 __attribute__((ext_vector_type(16)));
typedef unsigned int uint32x4 __attribute__((ext_vector_type(4)));

__device__ __forceinline__ unsigned short f2h(float x) {
    _Float16 h = (_Float16)x;
    return __builtin_bit_cast(unsigned short, h);
}

__device__ __forceinline__ unsigned cvtpk(float a, float b) {
    auto r = __builtin_amdgcn_cvt_pkrtz(a, b);      // low half = a, high = b
    return __builtin_bit_cast(unsigned, r);
}

// ---------------- W -> fp16 (single pass; absmax-verified R10) ----------------
__global__ __launch_bounds__(256) void prep_kernel(
    const float* __restrict__ Wq, const float* __restrict__ Wk, const float* __restrict__ Wv,
    unsigned short* __restrict__ Wh)
{
    int idx = blockIdx.x * 256 + threadIdx.x;   // 3*CH*CH = 196608
    if (idx >= 3 * CH * CH) return;
    int p = idx >> 16, oc = idx & 65535;
    const float* W = (p == 0) ? Wq : ((p == 1) ? Wk : Wv);
    Wh[idx] = f2h(W[oc]);
}

// ---------------- x fp32 [b][c][n] -> xT fp16 [b][n][c] ----------------
__global__ __launch_bounds__(256) void xt_kernel(
    const float* __restrict__ x, unsigned short* __restrict__ xT)
{
    const int b = blockIdx.z, c0 = blockIdx.y * 32, n0 = blockIdx.x * 32;
    __shared__ float T[32][33];
    const int t = threadIdx.x;
    {
        int c = t >> 3, n4 = (t & 7) * 4;
        float4 v4 = *(const float4*)&x[((size_t)b * CH + c0 + c) * NN + n0 + n4];
        T[c][n4 + 0] = v4.x; T[c][n4 + 1] = v4.y;
        T[c][n4 + 2] = v4.z; T[c][n4 + 3] = v4.w;
    }
    __syncthreads();
    {
        int n = t >> 3, c4 = (t & 7) * 4;
        ushort4 o;
        o.x = f2h(T[c4 + 0][n]); o.y = f2h(T[c4 + 1][n]);
        o.z = f2h(T[c4 + 2][n]); o.w = f2h(T[c4 + 3][n]);
        *(ushort4*)&xT[((size_t)b * NN + n0 + n) * CH + c0 + c4] = o;
    }
}

// ---------------- pos^T fp16: pT[h][n][d] ----------------
__global__ __launch_bounds__(256) void pos_kernel(
    const float* __restrict__ rel_h, const float* __restrict__ rel_w,
    unsigned short* __restrict__ pT)
{
    int idx = blockIdx.x * 256 + threadIdx.x;     // NH*NN*DH = 262144
    if (idx >= NH * NN * DH) return;
    int d = idx & 63, n = (idx >> 6) & (NN - 1), h = idx >> 16;
    float val = rel_w[(h * DH + d) * 32 + (n >> 5)] + rel_h[(h * DH + d) * 32 + (n & 31)];
    pT[idx] = f2h(val);
}

// ---------------- projection via fp16 MFMA (R10 standalone, verified) ----------------
__global__ __launch_bounds__(256) void proj_kernel(
    const unsigned short* __restrict__ xT,
    const unsigned short* __restrict__ Wh,
    const float* __restrict__ bq, const float* __restrict__ bk, const float* __restrict__ bv,
    unsigned short* __restrict__ qT, unsigned short* __restrict__ kT,
    unsigned short* __restrict__ vH)
{
    const int bz = blockIdx.z;
    const int b = bz / 3, p = bz % 3;
    const int n0 = blockIdx.x * 64;
    const int o0 = blockIdx.y * 64;
    const float* bias = (p == 0) ? bq : ((p == 1) ? bk : bv);

    __shared__ __align__(16) unsigned short Xs[64][72];
    __shared__ __align__(16) unsigned short Whs[64][72];

    const int tid = threadIdx.x;
    const int wid = tid >> 6, lane = tid & 63;
    const int g = lane >> 4, lr = lane & 15;

    const unsigned short* xb  = xT + (size_t)b * NN * CH;
    const unsigned short* Whp = Wh + (size_t)p * CH * CH;

    const f32x4 z4 = {0.f, 0.f, 0.f, 0.f};
    f32x4 acc[4] = {z4, z4, z4, z4};

    for (int cs = 0; cs < 4; ++cs) {
        const int c0 = cs * 64;
        __syncthreads();
        #pragma unroll
        for (int rep = 0; rep < 2; ++rep) {
            int f = rep * 256 + tid;
            int r = f >> 3, s = f & 7;
            *(uint4*)&Xs[r][s * 8]  = *(const uint4*)&xb[(size_t)(n0 + r) * CH + c0 + s * 8];
            *(uint4*)&Whs[r][s * 8] = *(const uint4*)&Whp[(size_t)(o0 + r) * CH + c0 + s * 8];
        }
        __syncthreads();
        #pragma unroll
        for (int ks = 0; ks < 2; ++ks) {
            f16x8 ah = *(const f16x8*)&Whs[wid * 16 + lr][ks * 32 + g * 8];
            #pragma unroll
            for (int fc = 0; fc < 4; ++fc) {
                f16x8 bx = *(const f16x8*)&Xs[fc * 16 + lr][ks * 32 + g * 8];
                acc[fc] = __builtin_amdgcn_mfma_f32_16x16x32_f16(ah, bx, acc[fc], 0, 0, 0);
            }
        }
    }

    float bb[4];
    #pragma unroll
    for (int rr = 0; rr < 4; ++rr) bb[rr] = bias[o0 + wid * 16 + g * 4 + rr];

    if (p < 2) {
        const float scale = (p == 0) ? 1.44269504088896f : 1.0f;   // fold log2e into q
        __syncthreads();
        unsigned short (*Os)[72] = Whs;     // reuse as [n-local][o-local]
        #pragma unroll
        for (int fc = 0; fc < 4; ++fc)
            #pragma unroll
            for (int rr = 0; rr < 4; ++rr)
                Os[fc * 16 + lr][wid * 16 + g * 4 + rr] = f2h((acc[fc][rr] + bb[rr]) * scale);
        __syncthreads();
        unsigned short* dst = ((p == 0) ? qT : kT) + ((size_t)(b * NH + blockIdx.y) * NN + n0) * DH;
        #pragma unroll
        for (int rep = 0; rep < 2; ++rep) {
            int f = rep * 256 + tid;
            int r = f >> 3, s = f & 7;
            *(uint4*)&dst[(size_t)r * DH + s * 8] = *(const uint4*)&Os[r][s * 8];
        }
    } else {
        unsigned short* dv = vH + (size_t)b * CH * NN;
        #pragma unroll
        for (int fc = 0; fc < 4; ++fc)
            #pragma unroll
            for (int rr = 0; rr < 4; ++rr) {
                int o = o0 + wid * 16 + g * 4 + rr;
                dv[(size_t)o * NN + n0 + fc * 16 + lr] = f2h(acc[fc][rr] + bb[rr]);
            }
    }
}

// ---------------- repack K-ext into MFMA-fragment-major order ----------------
// Byte-exact replay of R9's verified composition: STAGE(K) -> LDS(XOR-swizzle) ->
// A-frag read -> store what each lane read at [bh][jt][ks][grp][lane][8].
// attn then loads frags as base + lane*16B (fully coalesced, L2-hit).
__global__ __launch_bounds__(256) void repack_k_kernel(
    const unsigned short* __restrict__ qT, const unsigned short* __restrict__ kT,
    unsigned short* __restrict__ kF)
{
    const int jt = blockIdx.x;        // 0..15
    const int bh = blockIdx.y;        // 0..63
    const int b = bh >> 2, h = bh & 3;
    const int jb = jt * 64;

    __shared__ __align__(16) unsigned short Kb[64 * 128];   // 16 KB

    const int tid = threadIdx.x;
    const int wid = tid >> 6, lane = tid & 63;
    const int l31 = lane & 31, hi = lane >> 5;
    const int srow = tid >> 4, sslot = tid & 15;

    const size_t bhNN = (size_t)(b * NH + h) * NN;
    const unsigned short* qTb = qT + bhNN * DH;
    const unsigned short* kTb = kT + bhNN * DH;

    #pragma unroll
    for (int rep = 0; rep < 4; ++rep) {
        int row = rep * 16 + srow;
        const unsigned short* src = ((sslot < 8) ? kTb : qTb)
            + (size_t)(jb + row) * DH + (sslot & 7) * 8;
        uint4 v = *(const uint4*)src;
        *(uint4*)&Kb[row * 128 + ((sslot ^ (row & 15)) << 3)] = v;
    }
    __syncthreads();

    #pragma unroll
    for (int kk = 0; kk < 2; ++kk) {
        int ks = wid * 2 + kk;
        #pragma unroll
        for (int grp = 0; grp < 2; ++grp) {
            int row = grp * 32 + l31;
            int slot = ks * 2 + hi;
            uint4 v = *(const uint4*)&Kb[row * 128 + ((slot ^ (row & 15)) << 3)];
            size_t dst = ((((size_t)bh * 16 + jt) * 8 + ks) * 2 + grp) * 512 + (size_t)lane * 8;
            *(uint4*)&kF[dst] = v;
        }
    }
}

// ---------------- repack V into fragment-major order [bh][jt][u][which][lane][8] ----------------
__global__ __launch_bounds__(256) void repack_v_kernel(
    const unsigned short* __restrict__ vH, unsigned short* __restrict__ vF)
{
    const int jt = blockIdx.x;
    const int bh = blockIdx.y;
    const int b = bh >> 2, h = bh & 3;
    const int jb = jt * 64;

    __shared__ __align__(16) unsigned short Vb[32 * 128];   // 8 KB

    const int tid = threadIdx.x;
    const int wid = tid >> 6, lane = tid & 63;
    const int l31 = lane & 31, hi = lane >> 5;
    const int srow = tid >> 4, sslot = tid & 15;

    const unsigned short* vb = vH + ((size_t)b * CH + h * DH) * NN;

    const int vc = sslot & 7;
    const int vM = ((vc >> 1) << 2) + (vc & 1) + ((sslot & 8) << 1);
    const int vs8 = vM >> 1;
    const int vnib = (vM & 1) * 4;

    #pragma unroll
    for (int rep = 0; rep < 2; ++rep) {
        int row = rep * 16 + srow;
        int d = row + ((sslot & 8) << 2);
        uint4 v = *(const uint4*)&vb[(size_t)d * NN + jb + (sslot & 7) * 8];
        uint2 vlo; vlo.x = v.x; vlo.y = v.y;
        uint2 vhi2; vhi2.x = v.z; vhi2.y = v.w;
        *(uint2*)&Vb[row * 128 + ((vs8 ^ (row & 15)) << 3) + vnib] = vlo;
        *(uint2*)&Vb[row * 128 + (((vs8 + 1) ^ (row & 15)) << 3) + vnib] = vhi2;
    }
    __syncthreads();

    {
        int u = wid;                      // 0..3
        #pragma unroll
        for (int which = 0; which < 2; ++which) {
            int slot = which * 8 + u * 2 + hi;
            int row = l31;
            uint4 v = *(const uint4*)&Vb[row * 128 + ((slot ^ (row & 15)) << 3)];
            size_t dst = ((((size_t)bh * 16 + jt) * 4 + u) * 2 + which) * 512 + (size_t)lane * 8;
            *(uint4*)&vF[dst] = v;
        }
    }
}

// ---------------- fused flash attention: BARRIER-FREE, fragment-major global loads ----------------
// R11 diagnosis: attn latency/sync-bound (all pipes <40%). Fix: K/V pre-repacked into
// frag-major order -> per-wave A/B-frag loads are base+lane*16B (coalesced, L2-hit).
// Main loop: NO LDS, NO barriers; 8 independent waves/CU hide L2 latency by TLP.
// Same math/layout bytes as verified R9 (repack replays its staging+read composition).
__global__ __launch_bounds__(256, 2) void attn_kernel(
    const unsigned short* __restrict__ qT, const unsigned short* __restrict__ pT,
    const unsigned short* __restrict__ kF, const unsigned short* __restrict__ vF,
    float* __restrict__ out)
{
    const int wg = blockIdx.x;                       // 0..511
    const int bh = (wg & 7) * 8 + ((wg >> 3) & 7);   // XCD-bijective: 8 (b,h) per XCD
    const int it = wg >> 6;                          // 0..7
    const int b = bh >> 2, h = bh & 3;
    const int i0 = it * 128;

    __shared__ __align__(16) float Epi[64 * 132];    // 33.8 KB epilogue transpose
    __shared__ __align__(16) float Lbuf[128];
    __shared__ float ScBuf[4][32];

    const int tid = threadIdx.x;
    const int wid = tid >> 6, lane = tid & 63;
    const int l31 = lane & 31, hi = lane >> 5;

    const size_t bhNN = (size_t)(b * NH + h) * NN;
    const unsigned short* qTb = qT + bhNN * DH;
    const unsigned short* pTb = pT + (size_t)h * NN * DH;

    // Q-ext B-fragments (cols i), loaded once
    f16x8 bQ[8];
    {
        const int i = i0 + wid * 32 + l31;
        #pragma unroll
        for (int ks = 0; ks < 8; ++ks) {
            int d0 = ks * 16 + hi * 8;
            const unsigned short* src = (d0 < 64) ? &qTb[(size_t)i * DH + d0]
                                                  : &pTb[(size_t)i * DH + d0 - 64];
            bQ[ks] = *(const f16x8*)src;
        }
    }

    const unsigned short* kFb = kF + (size_t)bh * 16 * 8192 + (size_t)lane * 8;
    const unsigned short* vFb = vF + (size_t)bh * 16 * 4096 + (size_t)lane * 8;

    f32x16 O0 = {}, O1 = {};
    float m_run = -1e30f, l_run = 0.f;

    for (int t = 0; t < 16; ++t) {
        const unsigned short* kt = kFb + (size_t)t * 8192;
        const unsigned short* vt = vFb + (size_t)t * 4096;

        // ---- issue all 24 frag loads (independent; coalesced 16B/lane) ----
        f16x8 a0[8], a1[8];
        #pragma unroll
        for (int ks = 0; ks < 8; ++ks) {
            a0[ks] = *(const f16x8*)(kt + ks * 1024);
            a1[ks] = *(const f16x8*)(kt + ks * 1024 + 512);
        }
        f16x8 vf0[4], vf1[4];
        #pragma unroll
        for (int u = 0; u < 4; ++u) {
            vf0[u] = *(const f16x8*)(vt + u * 1024);
            vf1[u] = *(const f16x8*)(vt + u * 1024 + 512);
        }

        // ---- QK^T (swapped): two 32x32 S^T subtiles ----
        f32x16 s0 = {}, s1 = {};
        __builtin_amdgcn_s_setprio(1);
        #pragma unroll
        for (int ks = 0; ks < 8; ++ks) {
            s0 = __builtin_amdgcn_mfma_f32_32x32x16_f16(a0[ks], bQ[ks], s0, 0, 0, 0);
            s1 = __builtin_amdgcn_mfma_f32_32x32x16_f16(a1[ks], bQ[ks], s1, 0, 0, 0);
        }
        __builtin_amdgcn_s_setprio(0);

        // ---- defer-max online softmax (log2 domain), fully in-lane ----
        float fm = s0[0];
        #pragma unroll
        for (int r = 1; r < 16; ++r) fm = fmaxf(fm, s0[r]);
        #pragma unroll
        for (int r = 0; r < 16; ++r) fm = fmaxf(fm, s1[r]);

        if (!__all(fm <= m_run + 8.f)) {
            float fmf = fmaxf(fm, __shfl_xor(fm, 32));   // pair-lane: full row max
            float mn = fmaxf(m_run, fmf);
            float sc = exp2f(m_run - mn);
            m_run = mn;
            l_run *= sc;
            if (lane < 32) ScBuf[wid][lane] = sc;        // sc for softmax row i = lane
            #pragma unroll
            for (int r = 0; r < 16; ++r) {
                int irow = (r & 3) + 8 * (r >> 2) + 4 * hi;
                float scv = ScBuf[wid][irow];
                O0[r] *= scv; O1[r] *= scv;
            }
        }

        // ---- P = exp2(S - m): pack fp16 pairs, sum in-lane ----
        unsigned c0[8], c1[8];
        float ps = 0.f;
        #pragma unroll
        for (int m = 0; m < 8; ++m) {
            float pa = exp2f(s0[2 * m]     - m_run);
            float pb = exp2f(s0[2 * m + 1] - m_run);
            float pc = exp2f(s1[2 * m]     - m_run);
            float pd = exp2f(s1[2 * m + 1] - m_run);
            ps += (pa + pb) + (pc + pd);
            c0[m] = cvtpk(pa, pb);
            c1[m] = cvtpk(pc, pd);
        }
        l_run += ps;

        // ---- PV A-frags: lane's own words, zero exchange ----
        f16x8 pA[2][2];
        #pragma unroll
        for (int js = 0; js < 2; ++js) {
            unsigned* c = js ? c1 : c0;
            #pragma unroll
            for (int ksi = 0; ksi < 2; ++ksi) {
                uint32x4 w = { c[ksi * 4 + 0], c[ksi * 4 + 1], c[ksi * 4 + 2], c[ksi * 4 + 3] };
                pA[js][ksi] = __builtin_bit_cast(f16x8, w);
            }
        }

        // ---- PV: O[i][d] += P * V  (u = js*2 + ksi) ----
        __builtin_amdgcn_s_setprio(1);
        #pragma unroll
        for (int js = 0; js < 2; ++js) {
            #pragma unroll
            for (int ksi = 0; ksi < 2; ++ksi) {
                int u = js * 2 + ksi;
                O0 = __builtin_amdgcn_mfma_f32_32x32x16_f16(pA[js][ksi], vf0[u], O0, 0, 0, 0);
                O1 = __builtin_amdgcn_mfma_f32_32x32x16_f16(pA[js][ksi], vf1[u], O1, 0, 0, 0);
            }
        }
        __builtin_amdgcn_s_setprio(0);
    }

    // ---- epilogue: pair-sum l, LDS transpose, normalized coalesced store ----
    float l_full = l_run + __shfl_xor(l_run, 32);
    float invl = 1.0f / l_full;
    if (lane < 32) Lbuf[wid * 32 + lane] = invl;
    #pragma unroll
    for (int r = 0; r < 16; ++r) {
        int irow = (r & 3) + 8 * (r >> 2) + 4 * hi;
        int ilocal = wid * 32 + irow;
        Epi[(l31) * 132 + ilocal]      = O0[r];
        Epi[(32 + l31) * 132 + ilocal] = O1[r];
    }
    __syncthreads();
    float* ob = out + ((size_t)b * CH + h * DH) * NN + i0;
    #pragma unroll
    for (int rep = 0; rep < 8; ++rep) {
        int f = rep * 256 + tid;
        int d = f >> 5, q = f & 31;
        float4 v4 = *(const float4*)&Epi[d * 132 + q * 4];
        float4 iv = *(const float4*)&Lbuf[q * 4];
        v4.x *= iv.x; v4.y *= iv.y; v4.z *= iv.z; v4.w *= iv.w;
        *(float4*)&ob[(size_t)d * NN + q * 4] = v4;
    }
}

extern "C" void kernel_launch(void* const* d_in, const int* in_sizes, int n_in,
                              void* d_out, int out_size, void* d_ws, size_t ws_size,
                              hipStream_t stream) {
    const float* x     = (const float*)d_in[0];
    const float* Wq    = (const float*)d_in[1];
    const float* bq    = (const float*)d_in[2];
    const float* Wk    = (const float*)d_in[3];
    const float* bk    = (const float*)d_in[4];
    const float* Wv    = (const float*)d_in[5];
    const float* bv    = (const float*)d_in[6];
    const float* rel_h = (const float*)d_in[7];
    const float* rel_w = (const float*)d_in[8];
    // d_in[9] (reg_qk), d_in[10] (reg_v): dead — reference discards the register-token group.
    float* out = (float*)d_out;

    const size_t SZ = (size_t)BB * NH * NN * DH;        // 4,194,304 halves
    unsigned short* qT = (unsigned short*)d_ws;         // 0
    unsigned short* kT = qT + SZ;                       // 4.19M
    unsigned short* vH = kT + SZ;                       // 8.39M
    unsigned short* pT = vH + SZ;                       // 12.58M (+262,144)
    unsigned short* xT = pT + (size_t)NH * NN * DH;     // 12.85M (+4.19M)
    unsigned short* Wh = xT + SZ;                       // 17.04M (+196,608)
    // Aliases (sequenced by kernel order; totals stay within the R2-proven 42.5MB):
    unsigned short* kF = xT;                            // 8.39M halves over dead xT+Wh+tail
    unsigned short* vF = kT;                            // 4.19M halves over dead kT

    prep_kernel<<<dim3((3 * CH * CH + 255) / 256), 256, 0, stream>>>(Wq, Wk, Wv, Wh);
    xt_kernel<<<dim3(NN / 32, CH / 32, BB), 256, 0, stream>>>(x, xT);
    pos_kernel<<<dim3((NH * NN * DH + 255) / 256), 256, 0, stream>>>(rel_h, rel_w, pT);
    proj_kernel<<<dim3(NN / 64, CH / 64, BB * 3), 256, 0, stream>>>(
        xT, Wh, bq, bk, bv, qT, kT, vH);
    repack_k_kernel<<<dim3(16, 64), 256, 0, stream>>>(qT, kT, kF);
    repack_v_kernel<<<dim3(16, 64), 256, 0, stream>>>(vH, vF);
    attn_kernel<<<dim3(512), 256, 0, stream>>>(qT, pT, kF, vF, out);
}

// Round 13
// 78.853 us; speedup vs baseline: 1.2066x; 1.1788x over previous
//
#include <hip/hip_runtime.h>

#define BB 16
#define CH 256
#define NH 4
#define DH 64
#define NN 1024

typedef _Float16 f16x8 __attribute__((ext_vector_type(8)));
typedef float f32x4 __attribute__((ext_vector_type(4)));
typedef float f32x16 __attribute__((ext_vector_type(16)));
typedef unsigned int uint32x4 __attribute__((ext_vector_type(4)));

__device__ __forceinline__ unsigned short f2h(float x) {
    _Float16 h = (_Float16)x;
    return __builtin_bit_cast(unsigned short, h);
}

__device__ __forceinline__ unsigned cvtpk(float a, float b) {
    auto r = __builtin_amdgcn_cvt_pkrtz(a, b);      // low half = a, high = b
    return __builtin_bit_cast(unsigned, r);
}

// ---------------- W -> fp16 (single pass; absmax-verified R10) ----------------
__global__ __launch_bounds__(256) void prep_kernel(
    const float* __restrict__ Wq, const float* __restrict__ Wk, const float* __restrict__ Wv,
    unsigned short* __restrict__ Wh)
{
    int idx = blockIdx.x * 256 + threadIdx.x;   // 3*CH*CH = 196608
    if (idx >= 3 * CH * CH) return;
    int p = idx >> 16, oc = idx & 65535;
    const float* W = (p == 0) ? Wq : ((p == 1) ? Wk : Wv);
    Wh[idx] = f2h(W[oc]);
}

// ---------------- x fp32 [b][c][n] -> xT fp16 [b][n][c] ----------------
__global__ __launch_bounds__(256) void xt_kernel(
    const float* __restrict__ x, unsigned short* __restrict__ xT)
{
    const int b = blockIdx.z, c0 = blockIdx.y * 32, n0 = blockIdx.x * 32;
    __shared__ float T[32][33];
    const int t = threadIdx.x;
    {
        int c = t >> 3, n4 = (t & 7) * 4;
        float4 v4 = *(const float4*)&x[((size_t)b * CH + c0 + c) * NN + n0 + n4];
        T[c][n4 + 0] = v4.x; T[c][n4 + 1] = v4.y;
        T[c][n4 + 2] = v4.z; T[c][n4 + 3] = v4.w;
    }
    __syncthreads();
    {
        int n = t >> 3, c4 = (t & 7) * 4;
        ushort4 o;
        o.x = f2h(T[c4 + 0][n]); o.y = f2h(T[c4 + 1][n]);
        o.z = f2h(T[c4 + 2][n]); o.w = f2h(T[c4 + 3][n]);
        *(ushort4*)&xT[((size_t)b * NN + n0 + n) * CH + c0 + c4] = o;
    }
}

// ---------------- pos^T fp16: pT[h][n][d] ----------------
__global__ __launch_bounds__(256) void pos_kernel(
    const float* __restrict__ rel_h, const float* __restrict__ rel_w,
    unsigned short* __restrict__ pT)
{
    int idx = blockIdx.x * 256 + threadIdx.x;     // NH*NN*DH = 262144
    if (idx >= NH * NN * DH) return;
    int d = idx & 63, n = (idx >> 6) & (NN - 1), h = idx >> 16;
    float val = rel_w[(h * DH + d) * 32 + (n >> 5)] + rel_h[(h * DH + d) * 32 + (n & 31)];
    pT[idx] = f2h(val);
}

// ---------------- projection + FUSED frag-major repack ----------------
// MFMA proj (R10-verified math), then epilogue writes acc into an LDS image laid
// out byte-identically to the verified repack kernels' staging, and emits kF/vF
// with the repack kernels' verbatim read-side code. kT/vH/qT eliminated.
// Image address bijections (checked vs repack semantics on concrete values):
//   Kb(j',dd,is_q): j'*128 + (((dd>>3)+8*is_q) ^ (j'&15))<<3) + (dd&7)
//   Vb(d,j'): vc=j'>>3, c4=(j'>>2)&1, c=j'&3, vM=((vc>>1)<<2)+(vc&1)+((d>>5)<<4);
//             (d&31)*128 + ((((vM>>1)+c4) ^ (d&15))<<3) + ((vM&1)<<2) + c
__global__ __launch_bounds__(256) void proj_kernel(
    const unsigned short* __restrict__ xT,
    const unsigned short* __restrict__ Wh,
    const float* __restrict__ bq, const float* __restrict__ bk, const float* __restrict__ bv,
    unsigned short* __restrict__ kF, unsigned short* __restrict__ vF)
{
    const int bz = blockIdx.z;
    const int b = bz / 3, p = bz % 3;
    const int jt = blockIdx.x;          // n-tile
    const int ot = blockIdx.y;          // o-tile == head
    const int n0 = jt * 64;
    const int o0 = ot * 64;
    const float* bias = (p == 0) ? bq : ((p == 1) ? bk : bv);

    __shared__ __align__(16) unsigned short Xs[64][72];
    __shared__ __align__(16) unsigned short Whs[64][72];
    __shared__ __align__(16) unsigned short Img[8192];     // 16 KB frag image

    const int tid = threadIdx.x;
    const int wid = tid >> 6, lane = tid & 63;
    const int g = lane >> 4, lr = lane & 15;
    const int l31 = lane & 31, hi = lane >> 5;

    const unsigned short* xb  = xT + (size_t)b * NN * CH;
    const unsigned short* Whp = Wh + (size_t)p * CH * CH;

    const f32x4 z4 = {0.f, 0.f, 0.f, 0.f};
    f32x4 acc[4] = {z4, z4, z4, z4};

    for (int cs = 0; cs < 4; ++cs) {
        const int c0 = cs * 64;
        __syncthreads();
        #pragma unroll
        for (int rep = 0; rep < 2; ++rep) {
            int f = rep * 256 + tid;
            int r = f >> 3, s = f & 7;
            *(uint4*)&Xs[r][s * 8]  = *(const uint4*)&xb[(size_t)(n0 + r) * CH + c0 + s * 8];
            *(uint4*)&Whs[r][s * 8] = *(const uint4*)&Whp[(size_t)(o0 + r) * CH + c0 + s * 8];
        }
        __syncthreads();
        #pragma unroll
        for (int ks = 0; ks < 2; ++ks) {
            f16x8 ah = *(const f16x8*)&Whs[wid * 16 + lr][ks * 32 + g * 8];
            #pragma unroll
            for (int fc = 0; fc < 4; ++fc) {
                f16x8 bx = *(const f16x8*)&Xs[fc * 16 + lr][ks * 32 + g * 8];
                acc[fc] = __builtin_amdgcn_mfma_f32_16x16x32_f16(ah, bx, acc[fc], 0, 0, 0);
            }
        }
    }

    float bb[4];
    #pragma unroll
    for (int rr = 0; rr < 4; ++rr) bb[rr] = bias[o0 + wid * 16 + g * 4 + rr];

    const int bh = b * NH + ot;

    if (p < 2) {
        const float scale = (p == 0) ? 1.44269504088896f : 1.0f;   // fold log2e into q
        const int qoff = (p == 0) ? 8 : 0;
        // write K-ext image (j' rows, dd dims)
        #pragma unroll
        for (int fc = 0; fc < 4; ++fc)
            #pragma unroll
            for (int rr = 0; rr < 4; ++rr) {
                int jl = fc * 16 + lr;
                int dd = wid * 16 + g * 4 + rr;
                Img[jl * 128 + ((((dd >> 3) + qoff) ^ (jl & 15)) << 3) + (dd & 7)] =
                    f2h((acc[fc][rr] + bb[rr]) * scale);
            }
        __syncthreads();
        // verbatim repack_k read-side (this block's 4 ks values)
        const int ks = ((p == 0) ? 4 : 0) + wid;
        #pragma unroll
        for (int grp = 0; grp < 2; ++grp) {
            int row = grp * 32 + l31;
            int slot = ks * 2 + hi;
            uint4 v = *(const uint4*)&Img[row * 128 + ((slot ^ (row & 15)) << 3)];
            size_t dst = ((((size_t)bh * 16 + jt) * 8 + ks) * 2 + grp) * 512 + (size_t)lane * 8;
            *(uint4*)&kF[dst] = v;
        }
    } else {
        // write V image (d, j')
        #pragma unroll
        for (int fc = 0; fc < 4; ++fc)
            #pragma unroll
            for (int rr = 0; rr < 4; ++rr) {
                int d  = wid * 16 + g * 4 + rr;
                int jl = fc * 16 + lr;
                int vc = jl >> 3, c4 = (jl >> 2) & 1, c = jl & 3;
                int vM = ((vc >> 1) << 2) + (vc & 1) + ((d >> 5) << 4);
                Img[(d & 31) * 128 + ((((vM >> 1) + c4) ^ (d & 15)) << 3) + ((vM & 1) << 2) + c] =
                    f2h(acc[fc][rr] + bb[rr]);
            }
        __syncthreads();
        // verbatim repack_v read-side
        const int u = wid;
        #pragma unroll
        for (int which = 0; which < 2; ++which) {
            int slot = which * 8 + u * 2 + hi;
            int row = l31;
            uint4 v = *(const uint4*)&Img[row * 128 + ((slot ^ (row & 15)) << 3)];
            size_t dst = ((((size_t)bh * 16 + jt) * 4 + u) * 2 + which) * 512 + (size_t)lane * 8;
            *(uint4*)&vF[dst] = v;
        }
    }
}

// ---------------- fused flash attention (R12-verified; bQ q-part now from kF) ----------------
// Barrier-free main loop, frag-major coalesced global loads, in-register softmax,
// zero-exchange PV. bQ[0..3] (q*log2e) = kF chunks [bh][it*2+(wid>>1)][4+ks][wid&1]
// (exact chunk identity: kF ks>=4 stores q[j][d] at j=jt*64+grp*32+l31, d=(ks-4)*16+hi*8+e).
__global__ __launch_bounds__(256, 2) void attn_kernel(
    const unsigned short* __restrict__ pT,
    const unsigned short* __restrict__ kF, const unsigned short* __restrict__ vF,
    float* __restrict__ out)
{
    const int wg = blockIdx.x;                       // 0..511
    const int bh = (wg & 7) * 8 + ((wg >> 3) & 7);   // XCD-bijective: 8 (b,h) per XCD
    const int it = wg >> 6;                          // 0..7
    const int b = bh >> 2, h = bh & 3;
    const int i0 = it * 128;

    __shared__ __align__(16) float Epi[64 * 132];    // 33.8 KB epilogue transpose
    __shared__ __align__(16) float Lbuf[128];
    __shared__ float ScBuf[4][32];

    const int tid = threadIdx.x;
    const int wid = tid >> 6, lane = tid & 63;
    const int l31 = lane & 31, hi = lane >> 5;

    const unsigned short* pTb = pT + (size_t)h * NN * DH;

    const unsigned short* kFb = kF + (size_t)bh * 16 * 8192 + (size_t)lane * 8;
    const unsigned short* vFb = vF + (size_t)bh * 16 * 4096 + (size_t)lane * 8;

    // Q-ext B-fragments: q*log2e from kF chunks (coalesced), pos from pT
    f16x8 bQ[8];
    {
        const int i = i0 + wid * 32 + l31;
        const unsigned short* qck = kFb + (size_t)(it * 2 + (wid >> 1)) * 8192;
        #pragma unroll
        for (int ksp = 0; ksp < 4; ++ksp) {
            bQ[ksp] = *(const f16x8*)(qck + (((4 + ksp) * 2 + (wid & 1)) * 512));
            bQ[4 + ksp] = *(const f16x8*)&pTb[(size_t)i * DH + ksp * 16 + hi * 8];
        }
    }

    f32x16 O0 = {}, O1 = {};
    float m_run = -1e30f, l_run = 0.f;

    for (int t = 0; t < 16; ++t) {
        const unsigned short* kt = kFb + (size_t)t * 8192;
        const unsigned short* vt = vFb + (size_t)t * 4096;

        // ---- issue all 24 frag loads (independent; coalesced 16B/lane) ----
        f16x8 a0[8], a1[8];
        #pragma unroll
        for (int ks = 0; ks < 8; ++ks) {
            a0[ks] = *(const f16x8*)(kt + ks * 1024);
            a1[ks] = *(const f16x8*)(kt + ks * 1024 + 512);
        }
        f16x8 vf0[4], vf1[4];
        #pragma unroll
        for (int u = 0; u < 4; ++u) {
            vf0[u] = *(const f16x8*)(vt + u * 1024);
            vf1[u] = *(const f16x8*)(vt + u * 1024 + 512);
        }

        // ---- QK^T (swapped): two 32x32 S^T subtiles ----
        f32x16 s0 = {}, s1 = {};
        __builtin_amdgcn_s_setprio(1);
        #pragma unroll
        for (int ks = 0; ks < 8; ++ks) {
            s0 = __builtin_amdgcn_mfma_f32_32x32x16_f16(a0[ks], bQ[ks], s0, 0, 0, 0);
            s1 = __builtin_amdgcn_mfma_f32_32x32x16_f16(a1[ks], bQ[ks], s1, 0, 0, 0);
        }
        __builtin_amdgcn_s_setprio(0);

        // ---- defer-max online softmax (log2 domain), fully in-lane ----
        float fm = s0[0];
        #pragma unroll
        for (int r = 1; r < 16; ++r) fm = fmaxf(fm, s0[r]);
        #pragma unroll
        for (int r = 0; r < 16; ++r) fm = fmaxf(fm, s1[r]);

        if (!__all(fm <= m_run + 8.f)) {
            float fmf = fmaxf(fm, __shfl_xor(fm, 32));   // pair-lane: full row max
            float mn = fmaxf(m_run, fmf);
            float sc = exp2f(m_run - mn);
            m_run = mn;
            l_run *= sc;
            if (lane < 32) ScBuf[wid][lane] = sc;        // sc for softmax row i = lane
            #pragma unroll
            for (int r = 0; r < 16; ++r) {
                int irow = (r & 3) + 8 * (r >> 2) + 4 * hi;
                float scv = ScBuf[wid][irow];
                O0[r] *= scv; O1[r] *= scv;
            }
        }

        // ---- P = exp2(S - m): pack fp16 pairs, sum in-lane ----
        unsigned c0[8], c1[8];
        float ps = 0.f;
        #pragma unroll
        for (int m = 0; m < 8; ++m) {
            float pa = exp2f(s0[2 * m]     - m_run);
            float pb = exp2f(s0[2 * m + 1] - m_run);
            float pc = exp2f(s1[2 * m]     - m_run);
            float pd = exp2f(s1[2 * m + 1] - m_run);
            ps += (pa + pb) + (pc + pd);
            c0[m] = cvtpk(pa, pb);
            c1[m] = cvtpk(pc, pd);
        }
        l_run += ps;

        // ---- PV A-frags: lane's own words, zero exchange ----
        f16x8 pA[2][2];
        #pragma unroll
        for (int js = 0; js < 2; ++js) {
            unsigned* c = js ? c1 : c0;
            #pragma unroll
            for (int ksi = 0; ksi < 2; ++ksi) {
                uint32x4 w = { c[ksi * 4 + 0], c[ksi * 4 + 1], c[ksi * 4 + 2], c[ksi * 4 + 3] };
                pA[js][ksi] = __builtin_bit_cast(f16x8, w);
            }
        }

        // ---- PV: O[i][d] += P * V  (u = js*2 + ksi) ----
        __builtin_amdgcn_s_setprio(1);
        #pragma unroll
        for (int js = 0; js < 2; ++js) {
            #pragma unroll
            for (int ksi = 0; ksi < 2; ++ksi) {
                int u = js * 2 + ksi;
                O0 = __builtin_amdgcn_mfma_f32_32x32x16_f16(pA[js][ksi], vf0[u], O0, 0, 0, 0);
                O1 = __builtin_amdgcn_mfma_f32_32x32x16_f16(pA[js][ksi], vf1[u], O1, 0, 0, 0);
            }
        }
        __builtin_amdgcn_s_setprio(0);
    }

    // ---- epilogue: pair-sum l, LDS transpose, normalized coalesced store ----
    float l_full = l_run + __shfl_xor(l_run, 32);
    float invl = 1.0f / l_full;
    if (lane < 32) Lbuf[wid * 32 + lane] = invl;
    #pragma unroll
    for (int r = 0; r < 16; ++r) {
        int irow = (r & 3) + 8 * (r >> 2) + 4 * hi;
        int ilocal = wid * 32 + irow;
        Epi[(l31) * 132 + ilocal]      = O0[r];
        Epi[(32 + l31) * 132 + ilocal] = O1[r];
    }
    __syncthreads();
    float* ob = out + ((size_t)b * CH + h * DH) * NN + i0;
    #pragma unroll
    for (int rep = 0; rep < 8; ++rep) {
        int f = rep * 256 + tid;
        int d = f >> 5, q = f & 31;
        float4 v4 = *(const float4*)&Epi[d * 132 + q * 4];
        float4 iv = *(const float4*)&Lbuf[q * 4];
        v4.x *= iv.x; v4.y *= iv.y; v4.z *= iv.z; v4.w *= iv.w;
        *(float4*)&ob[(size_t)d * NN + q * 4] = v4;
    }
}

extern "C" void kernel_launch(void* const* d_in, const int* in_sizes, int n_in,
                              void* d_out, int out_size, void* d_ws, size_t ws_size,
                              hipStream_t stream) {
    const float* x     = (const float*)d_in[0];
    const float* Wq    = (const float*)d_in[1];
    const float* bq    = (const float*)d_in[2];
    const float* Wk    = (const float*)d_in[3];
    const float* bk    = (const float*)d_in[4];
    const float* Wv    = (const float*)d_in[5];
    const float* bv    = (const float*)d_in[6];
    const float* rel_h = (const float*)d_in[7];
    const float* rel_w = (const float*)d_in[8];
    // d_in[9] (reg_qk), d_in[10] (reg_v): dead — reference discards the register-token group.
    float* out = (float*)d_out;

    unsigned short* kF = (unsigned short*)d_ws;                 // 8,388,608 halves
    unsigned short* vF = kF + (size_t)8388608;                  // 4,194,304
    unsigned short* pT = vF + (size_t)4194304;                  // 262,144
    unsigned short* xT = pT + (size_t)262144;                   // 4,194,304
    unsigned short* Wh = xT + (size_t)4194304;                  // 196,608  (total 34.5 MB)

    prep_kernel<<<dim3((3 * CH * CH + 255) / 256), 256, 0, stream>>>(Wq, Wk, Wv, Wh);
    xt_kernel<<<dim3(NN / 32, CH / 32, BB), 256, 0, stream>>>(x, xT);
    pos_kernel<<<dim3((NH * NN * DH + 255) / 256), 256, 0, stream>>>(rel_h, rel_w, pT);
    proj_kernel<<<dim3(NN / 64, CH / 64, BB * 3), 256, 0, stream>>>(
        xT, Wh, bq, bk, bv, kF, vF);
    attn_kernel<<<dim3(512), 256, 0, stream>>>(pT, kF, vF, out);
}